// Round 1
// baseline (1722.541 us; speedup 1.0000x reference)
//
#include <hip/hip_runtime.h>
#include <math.h>

#define DIM    64
#define TPB    256
#define MAXK   16
#define SLICES 32
#define NEG_INF (-3.0e38f)

// column swizzle: flip bit2 based on bit5 -> breaks the stride-32-float bank
// pattern for transposed-tile staging writes and b128 fragment reads.
__device__ __forceinline__ int swzcol(int n) { return n ^ (((n >> 5) & 1) << 2); }

// FIFO-updated memory row source: rows [wp, wp+B) mod N come from embeddings.
__device__ __forceinline__ const float* row_src(int r, const float* __restrict__ mem,
                                                const float* __restrict__ emb,
                                                int wp, int N, int B) {
  int diff = r - wp;
  if (diff < 0) diff += N;
  return (diff < B) ? (emb + (size_t)diff * DIM) : (mem + (size_t)r * DIM);
}

// Insert (v,id) into a descending sorted register list, stable (ties keep
// earlier index; callers feed candidates in ascending global index order).
__device__ __forceinline__ void insert_sorted(float (&lv)[MAXK], int (&li)[MAXK],
                                              float v, int id) {
#pragma unroll
  for (int k = MAXK - 1; k > 0; --k) {
    if (lv[k - 1] < v)      { lv[k] = lv[k - 1]; li[k] = li[k - 1]; }
    else if (lv[k] < v)     { lv[k] = v;         li[k] = id;        }
  }
  if (lv[0] < v) { lv[0] = v; li[0] = id; }
}

// ---------------- Kernel 1: inverse L2 norms of updated-memory rows + queries
__global__ void norms_kernel(const float* __restrict__ mem, const float* __restrict__ emb,
                             const float* __restrict__ qry, const int* __restrict__ wpp,
                             float* __restrict__ rm, float* __restrict__ rq,
                             int N, int B, int Q) {
  const int wp  = *wpp;
  const int row = blockIdx.x * (TPB / 8) + (threadIdx.x >> 3);
  const int sub = threadIdx.x & 7;             // 8 lanes per row
  if (row >= N + Q) return;
  const float* src = (row < N) ? row_src(row, mem, emb, wp, N, B)
                               : (qry + (size_t)(row - N) * DIM);
  const float4* s4 = (const float4*)src + sub * 2;
  float4 a = s4[0], b = s4[1];
  float ss = a.x*a.x + a.y*a.y + a.z*a.z + a.w*a.w
           + b.x*b.x + b.y*b.y + b.z*b.z + b.w*b.w;
  ss += __shfl_xor(ss, 1);
  ss += __shfl_xor(ss, 2);
  ss += __shfl_xor(ss, 4);
  if (sub == 0) {
    float inv = 1.0f / fmaxf(sqrtf(ss), 1e-12f);
    if (row < N) rm[row] = inv; else rq[row - N] = inv;
  }
}

// ---------------- Kernel 2: fused scores + per-slice online top-k -----------
// block: 256 threads (16x16), tile 128 queries x 128 rows, 8x8 per thread.
// grid.x = query-block (Q/128), grid.y = slice (SLICES). Each block streams
// N/SLICES rows in 128-row chunks; scanners (tid<128, one per query) keep a
// register top-MAXK list; partial lists written to workspace.
__global__ __launch_bounds__(TPB, 2)
void score_topk_kernel(const float* __restrict__ mem, const float* __restrict__ emb,
                       const float* __restrict__ qry, const int* __restrict__ wpp,
                       const float* __restrict__ rm, const float* __restrict__ rq,
                       float* __restrict__ pvals, int* __restrict__ pidx,
                       int N, int B, int Q, int K) {
  __shared__ float qT[64 * 128];      // qT[d][q'] transposed, col-swizzled
  __shared__ float uni[128 * 65];     // union: mT[d][n'] (64*128)  OR  scan buf [128][65]
  __shared__ float rqS[128];
  __shared__ float rmS[128];

  const int tid = threadIdx.x;
  const int ty  = tid >> 4;           // 0..15  (query sub-row)
  const int tx  = tid & 15;           // 0..15  (mem-col sub-col)
  const int qb  = blockIdx.x;
  const int s   = blockIdx.y;
  const int q0  = qb * 128;
  const int slice_rows = N / SLICES;
  const int nchunks    = slice_rows / 128;
  const int wp  = *wpp;

  // ---- stage query tile (transposed, swizzled) + rq ----
  {
    const int n = tid & 127, h = tid >> 7;     // n = query-in-tile, h = D half
    const int nswz = swzcol(n);
    const float4* s4 = (const float4*)(qry + (size_t)(q0 + n) * DIM) + h * 8;
#pragma unroll
    for (int i = 0; i < 8; ++i) {
      float4 v = s4[i];
      int d = h * 32 + i * 4;
      qT[(d + 0) * 128 + nswz] = v.x;
      qT[(d + 1) * 128 + nswz] = v.y;
      qT[(d + 2) * 128 + nswz] = v.z;
      qT[(d + 3) * 128 + nswz] = v.w;
    }
    if (tid < 128) rqS[tid] = rq[q0 + tid];
  }
  __syncthreads();

  float rqv[8];
#pragma unroll
  for (int i = 0; i < 8; ++i) rqv[i] = rqS[ty * 8 + i];

  float lv[MAXK]; int li[MAXK];
#pragma unroll
  for (int k = 0; k < MAXK; ++k) { lv[k] = NEG_INF; li[k] = 0; }

  const int pa0 = swzcol(ty * 8), pa1 = swzcol(ty * 8 + 4);
  const int pb0 = swzcol(tx * 8), pb1 = swzcol(tx * 8 + 4);
  const int sbase = s * slice_rows;

  for (int c = 0; c < nchunks; ++c) {
    const int gr0 = sbase + c * 128;
    // ---- stage memory chunk (transposed, swizzled) + rm ----
    {
      const int n = tid & 127, h = tid >> 7;
      const int nswz = swzcol(n);
      const float* srow = row_src(gr0 + n, mem, emb, wp, N, B);
      const float4* s4 = (const float4*)srow + h * 8;
#pragma unroll
      for (int i = 0; i < 8; ++i) {
        float4 v = s4[i];
        int d = h * 32 + i * 4;
        uni[(d + 0) * 128 + nswz] = v.x;
        uni[(d + 1) * 128 + nswz] = v.y;
        uni[(d + 2) * 128 + nswz] = v.z;
        uni[(d + 3) * 128 + nswz] = v.w;
      }
      if (tid < 128) rmS[tid] = rm[gr0 + tid];
    }
    __syncthreads();

    float rmv[8];
#pragma unroll
    for (int j = 0; j < 8; ++j) rmv[j] = rmS[tx * 8 + j];

    // ---- 128x128 fp32 GEMM tile, 8x8 per thread ----
    float acc[8][8];
#pragma unroll
    for (int i = 0; i < 8; ++i)
#pragma unroll
      for (int j = 0; j < 8; ++j) acc[i][j] = 0.0f;

#pragma unroll 4
    for (int d = 0; d < 64; ++d) {
      float a[8], b[8];
      *(float4*)&a[0] = *(const float4*)&qT[d * 128 + pa0];
      *(float4*)&a[4] = *(const float4*)&qT[d * 128 + pa1];
      *(float4*)&b[0] = *(const float4*)&uni[d * 128 + pb0];
      *(float4*)&b[4] = *(const float4*)&uni[d * 128 + pb1];
#pragma unroll
      for (int i = 0; i < 8; ++i)
#pragma unroll
        for (int j = 0; j < 8; ++j)
          acc[i][j] = fmaf(a[i], b[j], acc[i][j]);
    }

    // ---- scaled scores -> LDS (two 64-col halves, reusing uni), then scan ----
#pragma unroll 1
    for (int hh = 0; hh < 2; ++hh) {
      __syncthreads();                       // uni free (compute / prev scan done)
      if ((tx >> 3) == hh) {
        const int txl = tx & 7;
#pragma unroll
        for (int i = 0; i < 8; ++i) {
          const int rowoff = (ty * 8 + i) * 65 + txl * 8;
          const float rs = rqv[i];
#pragma unroll
          for (int j = 0; j < 8; ++j)
            uni[rowoff + j] = acc[i][j] * rs * rmv[j];
        }
      }
      __syncthreads();                       // scores visible
      if (tid < 128) {
        const float* srow2 = &uni[tid * 65];
        const int gb = gr0 + hh * 64;
        for (int n = 0; n < 64; n += 4) {
          float v0 = srow2[n + 0], v1 = srow2[n + 1];
          float v2 = srow2[n + 2], v3 = srow2[n + 3];
          float mx = fmaxf(fmaxf(v0, v1), fmaxf(v2, v3));
          if (mx > lv[MAXK - 1]) {
            if (v0 > lv[MAXK - 1]) insert_sorted(lv, li, v0, gb + n + 0);
            if (v1 > lv[MAXK - 1]) insert_sorted(lv, li, v1, gb + n + 1);
            if (v2 > lv[MAXK - 1]) insert_sorted(lv, li, v2, gb + n + 2);
            if (v3 > lv[MAXK - 1]) insert_sorted(lv, li, v3, gb + n + 3);
          }
        }
      }
    }
    __syncthreads();                         // scan done before next stage
  }

  // ---- write partial per-slice lists ----
  if (tid < 128) {
    const size_t base = ((size_t)(q0 + tid) * SLICES + s) * K;
#pragma unroll
    for (int k = 0; k < MAXK; ++k)
      if (k < K) { pvals[base + k] = lv[k]; pidx[base + k] = li[k]; }
  }
}

// ---------------- Kernel 3: merge 32 partial lists per query + gather -------
// one wave per query; lanes 0..31 hold slice heads, butterfly-max per round.
__global__ void merge_gather_kernel(const float* __restrict__ mem, const float* __restrict__ emb,
                                    const int* __restrict__ wpp,
                                    const float* __restrict__ pvals, const int* __restrict__ pidx,
                                    float* __restrict__ out_retr, float* __restrict__ out_vals,
                                    int N, int B, int Q, int K) {
  const int wave = threadIdx.x >> 6;
  const int lane = threadIdx.x & 63;
  const int q = blockIdx.x * 4 + wave;
  if (q >= Q) return;
  const int wp = *wpp;

  const int s = lane;
  const float* pv = pvals;
  const int*   pi = pidx;
  float hv = NEG_INF; int hidx = 0; int hk = 0;
  if (s < SLICES) {
    pv = pvals + ((size_t)q * SLICES + s) * K;
    pi = pidx  + ((size_t)q * SLICES + s) * K;
    hv = pv[0]; hidx = pi[0];
  }

  for (int r = 0; r < K; ++r) {
    float bv = hv; int bi = hidx; int bs = (s < SLICES) ? s : 0x7fffffff;
#pragma unroll
    for (int it = 0; it < 5; ++it) {
      const int m = 1 << it;
      float ov = __shfl_xor(bv, m);
      int   oi = __shfl_xor(bi, m);
      int   os = __shfl_xor(bs, m);
      if (ov > bv || (ov == bv && os < bs)) { bv = ov; bi = oi; bs = os; }
    }
    // broadcast winner from lane 0 to whole wave
    float bv_b = __shfl(bv, 0);
    int   bi_b = __shfl(bi, 0);
    int   bs_b = __shfl(bs, 0);
    if (lane == 0) out_vals[(size_t)q * K + r] = bv_b;
    if (s < SLICES && s == bs_b) {           // winner slice advances
      ++hk;
      if (hk < K) { hv = pv[hk]; hidx = pi[hk]; } else hv = NEG_INF;
    }
    const float* src = row_src(bi_b, mem, emb, wp, N, B);
    out_retr[((size_t)q * K + r) * DIM + lane] = src[lane];
  }
}

// ---------------- host launch ----------------
extern "C" void kernel_launch(void* const* d_in, const int* in_sizes, int n_in,
                              void* d_out, int out_size, void* d_ws, size_t ws_size,
                              hipStream_t stream) {
  const float* mem = (const float*)d_in[0];
  const float* emb = (const float*)d_in[1];
  const float* qry = (const float*)d_in[2];
  const int*   wpp = (const int*)d_in[3];
  // d_in[4] (top_k) unused on device; K derived from out_size.

  const int N = in_sizes[0] / DIM;     // 131072
  const int B = in_sizes[1] / DIM;     // 4096
  const int Q = in_sizes[2] / DIM;     // 2048
  int K = out_size / (Q * (DIM + 1));  // retrieved Q*K*64 + values Q*K
  if (K < 1) K = 1;
  if (K > MAXK) K = MAXK;              // supported range (actual K = 10)

  // workspace layout (floats): rm[N] | rq[Q] | pvals[Q*SLICES*K] | pidx[Q*SLICES*K]
  float* W     = (float*)d_ws;
  float* rm    = W;
  float* rq    = W + N;
  float* pvals = W + N + Q;
  int*   pidx  = (int*)(W + N + Q + (size_t)Q * SLICES * K);

  float* out_retr = (float*)d_out;
  float* out_vals = (float*)d_out + (size_t)Q * K * DIM;

  const int nb1 = (N + Q + 31) / 32;
  norms_kernel<<<nb1, TPB, 0, stream>>>(mem, emb, qry, wpp, rm, rq, N, B, Q);

  dim3 g2(Q / 128, SLICES);
  score_topk_kernel<<<g2, TPB, 0, stream>>>(mem, emb, qry, wpp, rm, rq,
                                            pvals, pidx, N, B, Q, K);

  merge_gather_kernel<<<Q / 4, TPB, 0, stream>>>(mem, emb, wpp, pvals, pidx,
                                                 out_retr, out_vals, N, B, Q, K);
}

// Round 2
// 995.500 us; speedup vs baseline: 1.7303x; 1.7303x over previous
//
#include <hip/hip_runtime.h>
#include <math.h>

#define DIM    64
#define MAXT   16            // per-scanner / per-slice list length
#define SLICES 32
#define QB     128           // queries per K2 block
#define CHUNK  64            // memory rows per K2 chunk
#define CAND   (SLICES*MAXT) // 512 candidates per query into K3
#define RES    64            // exact-rescore set size
#define NEG_INF (-3.0e38f)

typedef float f32x4 __attribute__((ext_vector_type(4)));
typedef short s16x8 __attribute__((ext_vector_type(8)));

__device__ __forceinline__ unsigned short f2bf(float f) {  // RNE f32->bf16
  unsigned u = __float_as_uint(f);
  u += 0x7fffu + ((u >> 16) & 1u);
  return (unsigned short)(u >> 16);
}

__device__ __forceinline__ const float* row_src(int r, const float* __restrict__ mem,
                                                const float* __restrict__ emb,
                                                int wp, int N, int B) {
  int diff = r - wp; if (diff < 0) diff += N;
  return (diff < B) ? (emb + (size_t)diff * DIM) : (mem + (size_t)r * DIM);
}

__device__ __forceinline__ void insert_sorted(float (&lv)[MAXT], int (&li)[MAXT],
                                              float v, int id) {
#pragma unroll
  for (int k = MAXT - 1; k > 0; --k) {
    if (lv[k - 1] < v)      { lv[k] = lv[k - 1]; li[k] = li[k - 1]; }
    else if (lv[k] < v)     { lv[k] = v;         li[k] = id;        }
  }
  if (lv[0] < v) { lv[0] = v; li[0] = id; }
}

// ---------------- K1: normalize updated memory + queries -> bf16; store inv-norms
__global__ __launch_bounds__(256)
void prep_kernel(const float* __restrict__ mem, const float* __restrict__ emb,
                 const float* __restrict__ qry, const int* __restrict__ wpp,
                 float* __restrict__ rm, float* __restrict__ rq,
                 unsigned short* __restrict__ Mn, unsigned short* __restrict__ Qn,
                 int N, int B, int Q) {
  const int wp  = *wpp;
  const int row = blockIdx.x * 32 + (threadIdx.x >> 3);
  const int sub = threadIdx.x & 7;                 // 8 lanes per row
  if (row >= N + Q) return;
  const float* src = (row < N) ? row_src(row, mem, emb, wp, N, B)
                               : (qry + (size_t)(row - N) * DIM);
  const float4* s4 = (const float4*)src + sub * 2;
  float4 a = s4[0], b = s4[1];
  float ss = a.x*a.x + a.y*a.y + a.z*a.z + a.w*a.w
           + b.x*b.x + b.y*b.y + b.z*b.z + b.w*b.w;
  ss += __shfl_xor(ss, 1);
  ss += __shfl_xor(ss, 2);
  ss += __shfl_xor(ss, 4);
  const float inv = 1.0f / fmaxf(sqrtf(ss), 1e-12f);
  uint4 o;
  o.x = (unsigned)f2bf(a.x*inv) | ((unsigned)f2bf(a.y*inv) << 16);
  o.y = (unsigned)f2bf(a.z*inv) | ((unsigned)f2bf(a.w*inv) << 16);
  o.z = (unsigned)f2bf(b.x*inv) | ((unsigned)f2bf(b.y*inv) << 16);
  o.w = (unsigned)f2bf(b.z*inv) | ((unsigned)f2bf(b.w*inv) << 16);
  unsigned short* dst = (row < N) ? (Mn + (size_t)row * DIM + sub * 8)
                                  : (Qn + (size_t)(row - N) * DIM + sub * 8);
  *(uint4*)dst = o;
  if (sub == 0) { if (row < N) rm[row] = inv; else rq[row - N] = inv; }
}

// ---------------- K2: bf16 MFMA scores + fused per-slice online top-16 ------
// 256 thr = 4 waves; tile QB=128 q x CHUNK=64 mem rows per step.
// A-frags (queries) live in registers for the whole kernel. B staged in LDS
// (single buffer, reg-staged with XOR swizzle). Scores go through padded LDS.
__global__ __launch_bounds__(256, 3)
void score_topk_kernel(const unsigned short* __restrict__ Mn,
                       const unsigned short* __restrict__ Qn,
                       float* __restrict__ pvals, int* __restrict__ pidx,
                       int N, int Q) {
  __shared__ unsigned short Mb[CHUNK * DIM];   // 8 KB, XOR-swizzled rows
  __shared__ float S[QB * 68];                 // 34.8 KB scores (pad 68) / merge buf

  const int tid = threadIdx.x;
  const int w = tid >> 6, l = tid & 63;
  const int q0 = blockIdx.x * QB;
  const int s  = blockIdx.y;
  const int slice_rows = N / SLICES;           // 4096
  const int nch = slice_rows / CHUNK;          // 64
  const int row_base = s * slice_rows;

  // ---- A fragments: 8 q-subtiles x 2 k-steps, loaded once from global ----
  s16x8 aF[8][2];
#pragma unroll
  for (int qt = 0; qt < 8; ++qt)
#pragma unroll
    for (int ks = 0; ks < 2; ++ks)
      aF[qt][ks] = *(const s16x8*)(Qn + (size_t)(q0 + qt*16 + (l & 15)) * DIM
                                      + ks*32 + (l >> 4)*8);

  // scanner state: thread t scans q-row t>>1, col half (t&1)
  float lv[MAXT]; int li[MAXT];
#pragma unroll
  for (int k = 0; k < MAXT; ++k) { lv[k] = NEG_INF; li[k] = 0; }
  const int sq = tid >> 1;
  const int sh = (tid & 1) * 32;

  // staging geometry: thread covers 16 shorts (32B): row n=tid>>2, blocks bb,bb+1
  const int stn = tid >> 2, stb = (tid & 3) * 2;
  char* MbB = (char*)Mb;

  // ---- stage chunk 0 ----
  {
    const unsigned short* src = Mn + (size_t)row_base * DIM + tid * 16;
    s16x8 r0 = *(const s16x8*)(src);
    s16x8 r1 = *(const s16x8*)(src + 8);
    *(s16x8*)(MbB + stn*128 + ((stb    ) ^ (stn & 7))*16) = r0;
    *(s16x8*)(MbB + stn*128 + ((stb + 1) ^ (stn & 7))*16) = r1;
  }
  __syncthreads();

  const int nl = 16*w + (l & 15);              // this lane's local B col (0..63)
  const int boff0 = nl*128 + (((l >> 4)    ) ^ (nl & 7))*16;   // k-step 0
  const int boff1 = nl*128 + ((4 + (l >> 4)) ^ (nl & 7))*16;   // k-step 1

  for (int c = 0; c < nch; ++c) {
    // prefetch next chunk into registers (hides HBM/L3 latency under compute)
    s16x8 r0, r1;
    const bool pf = (c + 1 < nch);
    if (pf) {
      const unsigned short* src = Mn + (size_t)(row_base + (c+1)*CHUNK) * DIM + tid * 16;
      r0 = *(const s16x8*)(src);
      r1 = *(const s16x8*)(src + 8);
    }
    // ---- B-frags + MFMA + score writes ----
    {
      s16x8 bF0 = *(const s16x8*)(MbB + boff0);
      s16x8 bF1 = *(const s16x8*)(MbB + boff1);
#pragma unroll
      for (int qt = 0; qt < 8; ++qt) {
        f32x4 acc = {0.f, 0.f, 0.f, 0.f};
        acc = __builtin_amdgcn_mfma_f32_16x16x32_bf16(aF[qt][0], bF0, acc, 0, 0, 0);
        acc = __builtin_amdgcn_mfma_f32_16x16x32_bf16(aF[qt][1], bF1, acc, 0, 0, 0);
        const int qrow = qt*16 + (l >> 4)*4;   // C/D: col=lane&15, row=(lane>>4)*4+reg
#pragma unroll
        for (int r = 0; r < 4; ++r)
          S[(qrow + r)*68 + nl] = acc[r];
      }
    }
    __syncthreads();                            // scores visible; Mb reads done
    if (pf) {                                   // overwrite Mb with next chunk
      *(s16x8*)(MbB + stn*128 + ((stb    ) ^ (stn & 7))*16) = r0;
      *(s16x8*)(MbB + stn*128 + ((stb + 1) ^ (stn & 7))*16) = r1;
    }
    // ---- scan this chunk's scores (all 256 threads, gated insert) ----
    {
      const float* srow = &S[sq*68 + sh];
      const int gb = row_base + c*CHUNK + sh;
#pragma unroll
      for (int n4 = 0; n4 < 32; n4 += 4) {
        float4 v = *(const float4*)(srow + n4);
        float mx = fmaxf(fmaxf(v.x, v.y), fmaxf(v.z, v.w));
        if (mx > lv[MAXT-1]) {
          if (v.x > lv[MAXT-1]) insert_sorted(lv, li, v.x, gb + n4 + 0);
          if (v.y > lv[MAXT-1]) insert_sorted(lv, li, v.y, gb + n4 + 1);
          if (v.z > lv[MAXT-1]) insert_sorted(lv, li, v.z, gb + n4 + 2);
          if (v.w > lv[MAXT-1]) insert_sorted(lv, li, v.w, gb + n4 + 3);
        }
      }
    }
    __syncthreads();                            // scan done; Mb[c+1] visible
  }

  // ---- dump scanner lists into S, merge halves, write per-slice top-16 ----
  {
    float* mv = S; int* mi = (int*)(S + 4096);
    const int base = sq*32 + (tid & 1)*16;
#pragma unroll
    for (int k = 0; k < MAXT; ++k) { mv[base + k] = lv[k]; mi[base + k] = li[k]; }
  }
  __syncthreads();
  if (tid < QB) {
    float* mv = S; int* mi = (int*)(S + 4096);
    const float* va = mv + tid*32; const int* ia = mi + tid*32;
    const float* vb = va + 16;     const int* ib = ia + 16;
    int pa = 0, pb = 0;
    const size_t g = ((size_t)(q0 + tid) * SLICES + s) * MAXT;
    for (int k = 0; k < MAXT; ++k) {
      bool ta;
      if (pb >= 16)      ta = true;
      else if (pa >= 16) ta = false;
      else ta = (va[pa] > vb[pb]) || (va[pa] == vb[pb] && ia[pa] < ib[pb]);
      if (ta) { pvals[g+k] = va[pa]; pidx[g+k] = ia[pa]; ++pa; }
      else    { pvals[g+k] = vb[pb]; pidx[g+k] = ib[pb]; ++pb; }
    }
  }
}

// ---------------- K3: per query: cut 512->64 by approx, exact fp32 rescore,
// in-wave sort-64, emit top-K values + gathered rows ------------------------
__global__ __launch_bounds__(256)
void merge_rescore_kernel(const float* __restrict__ mem, const float* __restrict__ emb,
                          const float* __restrict__ qry, const int* __restrict__ wpp,
                          const float* __restrict__ rm, const float* __restrict__ rq,
                          const float* __restrict__ pvals, const int* __restrict__ pidx,
                          float* __restrict__ out_retr, float* __restrict__ out_vals,
                          int N, int B, int Q, int K) {
  __shared__ float cv[CAND]; __shared__ int ci[CAND];
  __shared__ float ev[RES];  __shared__ int ei[RES];
  const int tid = threadIdx.x;
  const int q   = blockIdx.x;
  const int wp  = *wpp;

  for (int i = tid; i < CAND; i += 256) {
    cv[i] = pvals[(size_t)q * CAND + i];
    ci[i] = pidx [(size_t)q * CAND + i];
  }
  __syncthreads();

  // bitonic sort 512 descending by (value, then lower index first)
  for (int k = 2; k <= CAND; k <<= 1) {
    for (int j = k >> 1; j > 0; j >>= 1) {
      for (int i = tid; i < CAND; i += 256) {
        int p = i ^ j;
        if (p > i) {
          float a = cv[i], b = cv[p]; int x = ci[i], y = ci[p];
          bool aFirst = (a > b) || (a == b && x < y);
          bool up = ((i & k) == 0);
          if (up ? !aFirst : aFirst) { cv[i] = b; cv[p] = a; ci[i] = y; ci[p] = x; }
        }
      }
      __syncthreads();
    }
  }

  // exact fp32 rescore of approx-top-64 (wave 0), then in-wave bitonic sort 64
  if (tid < RES) {
    const int idx = ci[tid];
    const float* mr = row_src(idx, mem, emb, wp, N, B);
    const float* qr = qry + (size_t)q * DIM;
    float acc = 0.f;
#pragma unroll
    for (int d = 0; d < DIM; d += 4) {
      float4 m4 = *(const float4*)(mr + d);
      float4 q4 = *(const float4*)(qr + d);
      acc = fmaf(q4.x, m4.x, acc); acc = fmaf(q4.y, m4.y, acc);
      acc = fmaf(q4.z, m4.z, acc); acc = fmaf(q4.w, m4.w, acc);
    }
    float v = acc * rq[q] * rm[idx];
    int   id = idx;
    const int lane = tid;
#pragma unroll
    for (int k2 = 2; k2 <= RES; k2 <<= 1) {
#pragma unroll
      for (int j = k2 >> 1; j > 0; j >>= 1) {
        float ov = __shfl_xor(v, j); int oi = __shfl_xor(id, j);
        bool lower  = ((lane & j) == 0);
        bool aFirst = (v > ov) || (v == ov && id < oi);
        bool up     = ((lane & k2) == 0);
        bool keep   = up ? (lower == aFirst) : (lower != aFirst);
        if (!keep) { v = ov; id = oi; }
      }
    }
    ev[tid] = v; ei[tid] = id;
  }
  __syncthreads();

  for (int e = tid; e < K * DIM; e += 256) {
    const int kk = e >> 6, d = e & 63;
    const float* mr = row_src(ei[kk], mem, emb, wp, N, B);
    out_retr[((size_t)q * K + kk) * DIM + d] = mr[d];
  }
  if (tid < K) out_vals[(size_t)q * K + tid] = ev[tid];
}

// ---------------- host launch ----------------
extern "C" void kernel_launch(void* const* d_in, const int* in_sizes, int n_in,
                              void* d_out, int out_size, void* d_ws, size_t ws_size,
                              hipStream_t stream) {
  const float* mem = (const float*)d_in[0];
  const float* emb = (const float*)d_in[1];
  const float* qry = (const float*)d_in[2];
  const int*   wpp = (const int*)d_in[3];

  const int N = in_sizes[0] / DIM;     // 131072
  const int B = in_sizes[1] / DIM;     // 4096
  const int Q = in_sizes[2] / DIM;     // 2048
  int K = out_size / (Q * (DIM + 1));  // 10
  if (K < 1) K = 1;
  if (K > MAXT) K = MAXT;

  // workspace: rm[N] | rq[Q] | pvals[Q*512] | pidx[Q*512] | Mn bf16[N*64] | Qn bf16[Q*64]
  float* rm    = (float*)d_ws;
  float* rq    = rm + N;
  float* pvals = rq + Q;
  int*   pidx  = (int*)(pvals + (size_t)Q * CAND);
  unsigned short* Mn = (unsigned short*)(pidx + (size_t)Q * CAND);
  unsigned short* Qn = Mn + (size_t)N * DIM;

  float* out_retr = (float*)d_out;
  float* out_vals = (float*)d_out + (size_t)Q * K * DIM;

  prep_kernel<<<(N + Q) / 32, 256, 0, stream>>>(mem, emb, qry, wpp, rm, rq, Mn, Qn, N, B, Q);

  dim3 g2(Q / QB, SLICES);
  score_topk_kernel<<<g2, 256, 0, stream>>>(Mn, Qn, pvals, pidx, N, Q);

  merge_rescore_kernel<<<Q, 256, 0, stream>>>(mem, emb, qry, wpp, rm, rq,
                                              pvals, pidx, out_retr, out_vals,
                                              N, B, Q, K);
}

// Round 3
// 322.421 us; speedup vs baseline: 5.3425x; 3.0876x over previous
//
#include <hip/hip_runtime.h>
#include <math.h>

#define DIM    64
#define MAXT   16
#define SLICES 64
#define QB     128
#define CHUNK  64
#define CLCAP  1024
#define NEG_INF (-3.0e38f)
#define MARGIN 0.03f

typedef float f32x4 __attribute__((ext_vector_type(4)));
typedef short s16x8 __attribute__((ext_vector_type(8)));
typedef unsigned short u16;

__device__ __forceinline__ u16 f2bf(float f) {  // RNE f32->bf16
  unsigned u = __float_as_uint(f);
  u += 0x7fffu + ((u >> 16) & 1u);
  return (u16)(u >> 16);
}

__device__ __forceinline__ const float* row_src(int r, const float* __restrict__ mem,
                                                const float* __restrict__ emb,
                                                int wp, int N, int B) {
  int diff = r - wp; if (diff < 0) diff += N;
  return (diff < B) ? (emb + (size_t)diff * DIM) : (mem + (size_t)r * DIM);
}

// max across the 16-lane DPP row (lanes grouped by l>>4), all lanes get result
__device__ __forceinline__ float rowmax16(float v) {
  int x, y;
  x = __float_as_int(v);
  y = __builtin_amdgcn_update_dpp(x, x, 0x128, 0xF, 0xF, false); v = fmaxf(v, __int_as_float(y));
  x = __float_as_int(v);
  y = __builtin_amdgcn_update_dpp(x, x, 0x124, 0xF, 0xF, false); v = fmaxf(v, __int_as_float(y));
  x = __float_as_int(v);
  y = __builtin_amdgcn_update_dpp(x, x, 0x122, 0xF, 0xF, false); v = fmaxf(v, __int_as_float(y));
  x = __float_as_int(v);
  y = __builtin_amdgcn_update_dpp(x, x, 0x121, 0xF, 0xF, false); v = fmaxf(v, __int_as_float(y));
  return v;
}

// rank test: does (a_v, a_i) rank BELOW (v, id)?  (desc value, asc index)
__device__ __forceinline__ bool rank_below(float a_v, int a_i, float v, int id) {
  return (a_v < v) || (a_v == v && a_i > id);
}

__device__ __forceinline__ void insert_val(float (&lv)[MAXT], float v) {
#pragma unroll
  for (int k = MAXT - 1; k > 0; --k) {
    if (lv[k - 1] < v)      { lv[k] = lv[k - 1]; }
    else if (lv[k] < v)     { lv[k] = v;         }
  }
  if (lv[0] < v) lv[0] = v;
}

__device__ __forceinline__ void insert_pair(float (&lv)[MAXT], int (&li)[MAXT],
                                            float v, int id) {
#pragma unroll
  for (int k = MAXT - 1; k > 0; --k) {
    if (rank_below(lv[k - 1], li[k - 1], v, id)) { lv[k] = lv[k - 1]; li[k] = li[k - 1]; }
    else if (rank_below(lv[k], li[k], v, id))    { lv[k] = v;         li[k] = id;        }
  }
  if (rank_below(lv[0], li[0], v, id)) { lv[0] = v; li[0] = id; }
}

// ---------------- K1: normalize updated memory + queries -> bf16; store inv-norms
__global__ __launch_bounds__(256)
void prep_kernel(const float* __restrict__ mem, const float* __restrict__ emb,
                 const float* __restrict__ qry, const int* __restrict__ wpp,
                 float* __restrict__ rm, float* __restrict__ rq,
                 u16* __restrict__ Mn, u16* __restrict__ Qn,
                 int N, int B, int Q) {
  const int wp  = *wpp;
  const int row = blockIdx.x * 32 + (threadIdx.x >> 3);
  const int sub = threadIdx.x & 7;
  if (row >= N + Q) return;
  const float* src = (row < N) ? row_src(row, mem, emb, wp, N, B)
                               : (qry + (size_t)(row - N) * DIM);
  const float4* s4 = (const float4*)src + sub * 2;
  float4 a = s4[0], b = s4[1];
  float ss = a.x*a.x + a.y*a.y + a.z*a.z + a.w*a.w
           + b.x*b.x + b.y*b.y + b.z*b.z + b.w*b.w;
  ss += __shfl_xor(ss, 1);
  ss += __shfl_xor(ss, 2);
  ss += __shfl_xor(ss, 4);
  const float inv = 1.0f / fmaxf(sqrtf(ss), 1e-12f);
  uint4 o;
  o.x = (unsigned)f2bf(a.x*inv) | ((unsigned)f2bf(a.y*inv) << 16);
  o.y = (unsigned)f2bf(a.z*inv) | ((unsigned)f2bf(a.w*inv) << 16);
  o.z = (unsigned)f2bf(b.x*inv) | ((unsigned)f2bf(b.y*inv) << 16);
  o.w = (unsigned)f2bf(b.z*inv) | ((unsigned)f2bf(b.w*inv) << 16);
  u16* dst = (row < N) ? (Mn + (size_t)row * DIM + sub * 8)
                       : (Qn + (size_t)(row - N) * DIM + sub * 8);
  *(uint4*)dst = o;
  if (sub == 0) { if (row < N) rm[row] = inv; else rq[row - N] = inv; }
}

// ---------------- K2a: MFMA scores -> per-(query, 64-row-chunk) max (bf16) --
// grid (Q/128, SLICES); 4 waves; wave w owns q-subtiles 2w,2w+1, all 64 cols.
// B staged by global_load_lds (pre-swizzled source), double-buffered.
__global__ __launch_bounds__(256, 4)
void chunkmax_kernel(const u16* __restrict__ Mn, const u16* __restrict__ Qn,
                     u16* __restrict__ Cmax, int N, int nchTotal) {
  __shared__ u16 Mb[2][CHUNK * DIM];            // 2 x 8 KB
  const int tid = threadIdx.x;
  const int w = tid >> 6, l = tid & 63;
  const int q0 = blockIdx.x * QB;
  const int s  = blockIdx.y;
  const int slice_rows = N / SLICES;            // 2048
  const int nch = slice_rows / CHUNK;           // 32
  const int row_base = s * slice_rows;

  // A fragments: queries (2w+j)*16 + (l&15), k-offset ks*32 + (l>>4)*8
  s16x8 aF[2][2];
#pragma unroll
  for (int j = 0; j < 2; ++j)
#pragma unroll
    for (int ks = 0; ks < 2; ++ks)
      aF[j][ks] = *(const s16x8*)(Qn + (size_t)(q0 + (2*w + j)*16 + (l & 15)) * DIM
                                      + ks*32 + (l >> 4)*8);

  // staging: lane covers (row = w*16 + 8k + (l>>3), block l&7) <- global block (l&7)^(l>>3)
  const int srow = w*16 + (l >> 3);
  const int sblk = (l & 7) ^ (l >> 3);
  // B-frag read base: row (l&15), swizzled block (l>>4)^(l&7); ks=1 flips bit 6
  const int rbase = (l & 15)*128 + (((l >> 4) ^ (l & 7)) << 4);

  int buf = 0;
  {
    const u16* g0 = Mn + (size_t)(row_base + srow) * DIM + sblk*8;
    char* lb = (char*)&Mb[0][0] + w*2048;
    __builtin_amdgcn_global_load_lds((const __attribute__((address_space(1))) unsigned int*)g0,
                                     (__attribute__((address_space(3))) unsigned int*)lb, 16, 0, 0);
    __builtin_amdgcn_global_load_lds((const __attribute__((address_space(1))) unsigned int*)(g0 + 8*DIM),
                                     (__attribute__((address_space(3))) unsigned int*)(lb + 1024), 16, 0, 0);
  }
  __syncthreads();

  for (int c = 0; c < nch; ++c) {
    if (c + 1 < nch) {
      const u16* g0 = Mn + (size_t)(row_base + (c+1)*CHUNK + srow) * DIM + sblk*8;
      char* lb = (char*)&Mb[buf ^ 1][0] + w*2048;
      __builtin_amdgcn_global_load_lds((const __attribute__((address_space(1))) unsigned int*)g0,
                                       (__attribute__((address_space(3))) unsigned int*)lb, 16, 0, 0);
      __builtin_amdgcn_global_load_lds((const __attribute__((address_space(1))) unsigned int*)(g0 + 8*DIM),
                                       (__attribute__((address_space(3))) unsigned int*)(lb + 1024), 16, 0, 0);
    }
    const char* lb = (const char*)&Mb[buf][0];
    s16x8 bF[4][2];
#pragma unroll
    for (int nb = 0; nb < 4; ++nb) {
      bF[nb][0] = *(const s16x8*)(lb + rbase + nb*2048);
      bF[nb][1] = *(const s16x8*)(lb + (rbase ^ 64) + nb*2048);
    }
#pragma unroll
    for (int j = 0; j < 2; ++j) {
      f32x4 mx = {NEG_INF, NEG_INF, NEG_INF, NEG_INF};
#pragma unroll
      for (int nb = 0; nb < 4; ++nb) {
        f32x4 acc = {0.f, 0.f, 0.f, 0.f};
        acc = __builtin_amdgcn_mfma_f32_16x16x32_bf16(aF[j][0], bF[nb][0], acc, 0, 0, 0);
        acc = __builtin_amdgcn_mfma_f32_16x16x32_bf16(aF[j][1], bF[nb][1], acc, 0, 0, 0);
        mx[0] = fmaxf(mx[0], acc[0]); mx[1] = fmaxf(mx[1], acc[1]);
        mx[2] = fmaxf(mx[2], acc[2]); mx[3] = fmaxf(mx[3], acc[3]);
      }
      mx[0] = rowmax16(mx[0]); mx[1] = rowmax16(mx[1]);
      mx[2] = rowmax16(mx[2]); mx[3] = rowmax16(mx[3]);
      if ((l & 15) == 0) {
        const int gch = s*nch + c;
        const int qb_ = q0 + (2*w + j)*16 + (l >> 4)*4;
        Cmax[(size_t)(qb_ + 0)*nchTotal + gch] = f2bf(mx[0]);
        Cmax[(size_t)(qb_ + 1)*nchTotal + gch] = f2bf(mx[1]);
        Cmax[(size_t)(qb_ + 2)*nchTotal + gch] = f2bf(mx[2]);
        Cmax[(size_t)(qb_ + 3)*nchTotal + gch] = f2bf(mx[3]);
      }
    }
    __syncthreads();
    buf ^= 1;
  }
}

// ---------------- K2b: per query: tau = (K-th largest chunk-max) - MARGIN;
// ballot-compact chunk ids with max >= tau. One wave per query. -------------
__global__ __launch_bounds__(256)
void select_kernel(const u16* __restrict__ Cmax, u16* __restrict__ clist,
                   int* __restrict__ ccount, int nchTotal, int K) {
  const int w = threadIdx.x >> 6, l = threadIdx.x & 63;
  const int q = blockIdx.x * 4 + w;
  const u16* row = Cmax + (size_t)q * nchTotal;

  float v[32];
#pragma unroll
  for (int i = 0; i < 4; ++i) {
    s16x8 x = *(const s16x8*)(row + i*512 + l*8);
#pragma unroll
    for (int e = 0; e < 8; ++e)
      v[i*8 + e] = __uint_as_float(((unsigned)(u16)x[e]) << 16);
  }

  float lv[MAXT];
#pragma unroll
  for (int k = 0; k < MAXT; ++k) lv[k] = NEG_INF;
#pragma unroll
  for (int i = 0; i < 32; ++i)
    if (v[i] > lv[MAXT - 1]) insert_val(lv, v[i]);

  float mk = NEG_INF;
  for (int r = 0; r < K; ++r) {
    float bv = lv[0]; int bl = l;
#pragma unroll
    for (int it = 0; it < 6; ++it) {
      float ov = __shfl_xor(bv, 1 << it);
      int   ol = __shfl_xor(bl, 1 << it);
      if (ov > bv || (ov == bv && ol < bl)) { bv = ov; bl = ol; }
    }
    mk = bv;
    if (l == bl) {
#pragma unroll
      for (int k = 0; k < MAXT - 1; ++k) lv[k] = lv[k + 1];
      lv[MAXT - 1] = NEG_INF;
    }
  }
  const float tau = mk - MARGIN;

  u16* out = clist + (size_t)q * CLCAP;
  int cnt = 0;
#pragma unroll
  for (int i = 0; i < 4; ++i)
#pragma unroll
    for (int e = 0; e < 8; ++e) {
      const bool p = (v[i*8 + e] >= tau);
      const unsigned long long b = __ballot(p);
      if (p) {
        const int pos = cnt + (int)__popcll(b & ((1ull << l) - 1ull));
        if (pos < CLCAP) out[pos] = (u16)(i*512 + l*8 + e);
      }
      cnt += (int)__popcll(b);
    }
  if (l == 0) ccount[q] = (cnt > CLCAP) ? CLCAP : cnt;
}

// ---------------- K2c: exact fp32 rescore of selected chunks, top-K, gather -
// One wave per query; lane handles row chunk*64+lane. Exact same fmaf chain
// and v = acc*rq*rm ordering as the previously-passing kernel.
__global__ __launch_bounds__(256)
void rescore_kernel(const float* __restrict__ mem, const float* __restrict__ emb,
                    const float* __restrict__ qry, const int* __restrict__ wpp,
                    const float* __restrict__ rm, const float* __restrict__ rq,
                    const u16* __restrict__ clist, const int* __restrict__ ccount,
                    float* __restrict__ out_retr, float* __restrict__ out_vals,
                    int N, int B, int Q, int K) {
  const int w = threadIdx.x >> 6, l = threadIdx.x & 63;
  const int q = blockIdx.x * 4 + w;
  const int wp = *wpp;

  float4 qv[16];
  {
    const float4* qr4 = (const float4*)(qry + (size_t)q * DIM);
#pragma unroll
    for (int d = 0; d < 16; ++d) qv[d] = qr4[d];
  }
  const float rqv = rq[q];
  const int cnt = ccount[q];
  const u16* cl = clist + (size_t)q * CLCAP;

  float lv[MAXT]; int li[MAXT];
#pragma unroll
  for (int k = 0; k < MAXT; ++k) { lv[k] = NEG_INF; li[k] = 0x7fffffff; }

  for (int i = 0; i < cnt; ++i) {
    const int row = (int)cl[i] * CHUNK + l;
    const float* mr = row_src(row, mem, emb, wp, N, B);
    float acc = 0.f;
#pragma unroll
    for (int d = 0; d < 16; ++d) {
      float4 m4 = *(const float4*)(mr + d*4);
      float4 q4 = qv[d];
      acc = fmaf(q4.x, m4.x, acc); acc = fmaf(q4.y, m4.y, acc);
      acc = fmaf(q4.z, m4.z, acc); acc = fmaf(q4.w, m4.w, acc);
    }
    const float vv = acc * rqv * rm[row];
    if (rank_below(lv[MAXT - 1], li[MAXT - 1], vv, row)) insert_pair(lv, li, vv, row);
  }

  for (int r = 0; r < K; ++r) {
    float bv = lv[0]; int bi = li[0];
#pragma unroll
    for (int it = 0; it < 6; ++it) {
      float ov = __shfl_xor(bv, 1 << it);
      int   oi = __shfl_xor(bi, 1 << it);
      if (ov > bv || (ov == bv && oi < bi)) { bv = ov; bi = oi; }
    }
    if (li[0] == bi) {                 // unique owner lane advances
#pragma unroll
      for (int k = 0; k < MAXT - 1; ++k) { lv[k] = lv[k + 1]; li[k] = li[k + 1]; }
      lv[MAXT - 1] = NEG_INF; li[MAXT - 1] = 0x7fffffff;
    }
    if (l == 0) out_vals[(size_t)q * K + r] = bv;
    const float* sr = row_src(bi, mem, emb, wp, N, B);
    out_retr[((size_t)q * K + r) * DIM + l] = sr[l];
  }
}

// ---------------- host launch ----------------
extern "C" void kernel_launch(void* const* d_in, const int* in_sizes, int n_in,
                              void* d_out, int out_size, void* d_ws, size_t ws_size,
                              hipStream_t stream) {
  const float* mem = (const float*)d_in[0];
  const float* emb = (const float*)d_in[1];
  const float* qry = (const float*)d_in[2];
  const int*   wpp = (const int*)d_in[3];

  const int N = in_sizes[0] / DIM;     // 131072
  const int B = in_sizes[1] / DIM;     // 4096
  const int Q = in_sizes[2] / DIM;     // 2048
  int K = out_size / (Q * (DIM + 1));  // 10
  if (K < 1) K = 1;
  if (K > MAXT) K = MAXT;
  const int nchTotal = N / CHUNK;      // 2048

  // ws: rm[N] f32 | rq[Q] f32 | Cmax[Q*nch] bf16 | clist[Q*CLCAP] u16 |
  //     ccount[Q] int | Mn[N*64] bf16 | Qn[Q*64] bf16   (~30 MB)
  float* rm    = (float*)d_ws;
  float* rq    = rm + N;
  u16*   Cmax  = (u16*)(rq + Q);
  u16*   clist = Cmax + (size_t)Q * nchTotal;
  int*   ccount= (int*)(clist + (size_t)Q * CLCAP);
  u16*   Mn    = (u16*)(ccount + Q);
  u16*   Qn    = Mn + (size_t)N * DIM;

  float* out_retr = (float*)d_out;
  float* out_vals = (float*)d_out + (size_t)Q * K * DIM;

  prep_kernel<<<(N + Q) / 32, 256, 0, stream>>>(mem, emb, qry, wpp, rm, rq, Mn, Qn, N, B, Q);

  dim3 g2(Q / QB, SLICES);
  chunkmax_kernel<<<g2, 256, 0, stream>>>(Mn, Qn, Cmax, N, nchTotal);

  select_kernel<<<Q / 4, 256, 0, stream>>>(Cmax, clist, ccount, nchTotal, K);

  rescore_kernel<<<Q / 4, 256, 0, stream>>>(mem, emb, qry, wpp, rm, rq, clist, ccount,
                                            out_retr, out_vals, N, B, Q, K);
}

// Round 4
// 296.499 us; speedup vs baseline: 5.8096x; 1.0874x over previous
//
#include <hip/hip_runtime.h>
#include <math.h>

#define DIM    64
#define MAXT   16
#define SLICES 64
#define QB     128
#define CHUNK  64
#define CLCAP  1024
#define NEG_INF (-3.0e38f)
#define MARGIN 0.016f

typedef float f32x4 __attribute__((ext_vector_type(4)));
typedef short s16x8 __attribute__((ext_vector_type(8)));
typedef unsigned short u16;

__device__ __forceinline__ u16 f2bf(float f) {  // RNE f32->bf16
  unsigned u = __float_as_uint(f);
  u += 0x7fffu + ((u >> 16) & 1u);
  return (u16)(u >> 16);
}

__device__ __forceinline__ const float* row_src(int r, const float* __restrict__ mem,
                                                const float* __restrict__ emb,
                                                int wp, int N, int B) {
  int diff = r - wp; if (diff < 0) diff += N;
  return (diff < B) ? (emb + (size_t)diff * DIM) : (mem + (size_t)r * DIM);
}

// max across 16-lane DPP row, all lanes get result
__device__ __forceinline__ float rowmax16(float v) {
  int x, y;
  x = __float_as_int(v);
  y = __builtin_amdgcn_update_dpp(x, x, 0x128, 0xF, 0xF, false); v = fmaxf(v, __int_as_float(y));
  x = __float_as_int(v);
  y = __builtin_amdgcn_update_dpp(x, x, 0x124, 0xF, 0xF, false); v = fmaxf(v, __int_as_float(y));
  x = __float_as_int(v);
  y = __builtin_amdgcn_update_dpp(x, x, 0x122, 0xF, 0xF, false); v = fmaxf(v, __int_as_float(y));
  x = __float_as_int(v);
  y = __builtin_amdgcn_update_dpp(x, x, 0x121, 0xF, 0xF, false); v = fmaxf(v, __int_as_float(y));
  return v;
}

// rank test: does (a_v, a_i) rank BELOW (v, id)?  (desc value, asc index)
__device__ __forceinline__ bool rank_below(float a_v, int a_i, float v, int id) {
  return (a_v < v) || (a_v == v && a_i > id);
}

__device__ __forceinline__ void insert_val(float (&lv)[MAXT], float v) {
#pragma unroll
  for (int k = MAXT - 1; k > 0; --k) {
    if (lv[k - 1] < v)      { lv[k] = lv[k - 1]; }
    else if (lv[k] < v)     { lv[k] = v;         }
  }
  if (lv[0] < v) lv[0] = v;
}

__device__ __forceinline__ void insert_pair(float (&lv)[MAXT], int (&li)[MAXT],
                                            float v, int id) {
#pragma unroll
  for (int k = MAXT - 1; k > 0; --k) {
    if (rank_below(lv[k - 1], li[k - 1], v, id)) { lv[k] = lv[k - 1]; li[k] = li[k - 1]; }
    else if (rank_below(lv[k], li[k], v, id))    { lv[k] = v;         li[k] = id;        }
  }
  if (rank_below(lv[0], li[0], v, id)) { lv[0] = v; li[0] = id; }
}

// ---------------- K1: normalize updated memory + queries -> bf16; store inv-norms
__global__ __launch_bounds__(256)
void prep_kernel(const float* __restrict__ mem, const float* __restrict__ emb,
                 const float* __restrict__ qry, const int* __restrict__ wpp,
                 float* __restrict__ rm, float* __restrict__ rq,
                 u16* __restrict__ Mn, u16* __restrict__ Qn,
                 int N, int B, int Q) {
  const int wp  = *wpp;
  const int row = blockIdx.x * 32 + (threadIdx.x >> 3);
  const int sub = threadIdx.x & 7;
  if (row >= N + Q) return;
  const float* src = (row < N) ? row_src(row, mem, emb, wp, N, B)
                               : (qry + (size_t)(row - N) * DIM);
  const float4* s4 = (const float4*)src + sub * 2;
  float4 a = s4[0], b = s4[1];
  float ss = a.x*a.x + a.y*a.y + a.z*a.z + a.w*a.w
           + b.x*b.x + b.y*b.y + b.z*b.z + b.w*b.w;
  ss += __shfl_xor(ss, 1);
  ss += __shfl_xor(ss, 2);
  ss += __shfl_xor(ss, 4);
  const float inv = 1.0f / fmaxf(sqrtf(ss), 1e-12f);
  uint4 o;
  o.x = (unsigned)f2bf(a.x*inv) | ((unsigned)f2bf(a.y*inv) << 16);
  o.y = (unsigned)f2bf(a.z*inv) | ((unsigned)f2bf(a.w*inv) << 16);
  o.z = (unsigned)f2bf(b.x*inv) | ((unsigned)f2bf(b.y*inv) << 16);
  o.w = (unsigned)f2bf(b.z*inv) | ((unsigned)f2bf(b.w*inv) << 16);
  u16* dst = (row < N) ? (Mn + (size_t)row * DIM + sub * 8)
                       : (Qn + (size_t)(row - N) * DIM + sub * 8);
  *(uint4*)dst = o;
  if (sub == 0) { if (row < N) rm[row] = inv; else rq[row - N] = inv; }
}

// ---------------- K2a: MFMA scores -> per-(query, 64-row-chunk) max (bf16) --
// 1024 blocks; XCD-swizzled so all 16 query-blocks of a slice share an XCD
// (slice rows then L2-resident). Stage 128 rows (2 chunks) per iteration,
// double-buffered via global_load_lds (pre-swizzled source).
__global__ __launch_bounds__(256, 4)
void chunkmax_kernel(const u16* __restrict__ Mn, const u16* __restrict__ Qn,
                     u16* __restrict__ Cmax, int N, int nchTotal) {
  __shared__ u16 Mb[2][128 * DIM];              // 2 x 16 KB
  const int tid = threadIdx.x;
  const int w = tid >> 6, l = tid & 63;

  // bijective remap of 10-bit linear id: [2:0]=xcd, [6:3]=qb, [9:7]=sub
  const int id = blockIdx.x + gridDim.x * blockIdx.y;
  const int s  = (id & 7) * 8 + (id >> 7);      // slice 0..63, fixed per XCD
  const int qb = (id >> 3) & 15;                // query-block 0..15
  const int q0 = qb * QB;
  const int slice_rows = N / SLICES;            // 2048
  const int niter = slice_rows / 128;           // 16
  const int nch   = slice_rows / CHUNK;         // 32
  const int row_base = s * slice_rows;

  // A fragments: queries (2w+j)*16 + (l&15), k-offset ks*32 + (l>>4)*8
  s16x8 aF[2][2];
#pragma unroll
  for (int j = 0; j < 2; ++j)
#pragma unroll
    for (int ks = 0; ks < 2; ++ks)
      aF[j][ks] = *(const s16x8*)(Qn + (size_t)(q0 + (2*w + j)*16 + (l & 15)) * DIM
                                      + ks*32 + (l >> 4)*8);

  // staging: instr t covers rows w*32 + t*8 + (l>>3); global block (l&7)^(l>>3)
  const int sblk = (l & 7) ^ (l >> 3);
  // B-frag read base: row (l&15): byte = row*128 + (((l>>4) ^ (l&7))<<4)
  const int rb0 = (l & 15)*128 + (((l >> 4) ^ (l & 7)) << 4);

  int buf = 0;
  {
    char* lb = (char*)&Mb[0][0] + w*4096;
#pragma unroll
    for (int t = 0; t < 4; ++t) {
      const u16* g = Mn + (size_t)(row_base + w*32 + t*8 + (l >> 3)) * DIM + sblk*8;
      __builtin_amdgcn_global_load_lds((const __attribute__((address_space(1))) unsigned int*)g,
                                       (__attribute__((address_space(3))) unsigned int*)(lb + t*1024), 16, 0, 0);
    }
  }
  __syncthreads();

  for (int c2 = 0; c2 < niter; ++c2) {
    if (c2 + 1 < niter) {
      char* lb = (char*)&Mb[buf ^ 1][0] + w*4096;
      const int rb = row_base + (c2 + 1)*128;
#pragma unroll
      for (int t = 0; t < 4; ++t) {
        const u16* g = Mn + (size_t)(rb + w*32 + t*8 + (l >> 3)) * DIM + sblk*8;
        __builtin_amdgcn_global_load_lds((const __attribute__((address_space(1))) unsigned int*)g,
                                         (__attribute__((address_space(3))) unsigned int*)(lb + t*1024), 16, 0, 0);
      }
    }
    const char* lb = (const char*)&Mb[buf][0];
#pragma unroll
    for (int h = 0; h < 2; ++h) {               // two 64-row chunks in buffer
      s16x8 bF[4][2];
#pragma unroll
      for (int nb = 0; nb < 4; ++nb) {
        bF[nb][0] = *(const s16x8*)(lb + h*8192 + nb*2048 + rb0);
        bF[nb][1] = *(const s16x8*)(lb + h*8192 + nb*2048 + (rb0 ^ 64));
      }
#pragma unroll
      for (int j = 0; j < 2; ++j) {
        f32x4 mx = {NEG_INF, NEG_INF, NEG_INF, NEG_INF};
#pragma unroll
        for (int nb = 0; nb < 4; ++nb) {
          f32x4 acc = {0.f, 0.f, 0.f, 0.f};
          acc = __builtin_amdgcn_mfma_f32_16x16x32_bf16(aF[j][0], bF[nb][0], acc, 0, 0, 0);
          acc = __builtin_amdgcn_mfma_f32_16x16x32_bf16(aF[j][1], bF[nb][1], acc, 0, 0, 0);
          mx[0] = fmaxf(mx[0], acc[0]); mx[1] = fmaxf(mx[1], acc[1]);
          mx[2] = fmaxf(mx[2], acc[2]); mx[3] = fmaxf(mx[3], acc[3]);
        }
        mx[0] = rowmax16(mx[0]); mx[1] = rowmax16(mx[1]);
        mx[2] = rowmax16(mx[2]); mx[3] = rowmax16(mx[3]);
        if ((l & 15) == 0) {
          const int gch = s*nch + c2*2 + h;
          const int qb_ = q0 + (2*w + j)*16 + (l >> 4)*4;
          Cmax[(size_t)(qb_ + 0)*nchTotal + gch] = f2bf(mx[0]);
          Cmax[(size_t)(qb_ + 1)*nchTotal + gch] = f2bf(mx[1]);
          Cmax[(size_t)(qb_ + 2)*nchTotal + gch] = f2bf(mx[2]);
          Cmax[(size_t)(qb_ + 3)*nchTotal + gch] = f2bf(mx[3]);
        }
      }
    }
    __syncthreads();
    buf ^= 1;
  }
}

// ---------------- K2b: tau = (K-th largest chunk-max) - MARGIN; compact ids -
__global__ __launch_bounds__(256)
void select_kernel(const u16* __restrict__ Cmax, u16* __restrict__ clist,
                   int* __restrict__ ccount, int nchTotal, int K) {
  const int w = threadIdx.x >> 6, l = threadIdx.x & 63;
  const int q = blockIdx.x * 4 + w;
  const u16* row = Cmax + (size_t)q * nchTotal;

  float v[32];
#pragma unroll
  for (int i = 0; i < 4; ++i) {
    s16x8 x = *(const s16x8*)(row + i*512 + l*8);
#pragma unroll
    for (int e = 0; e < 8; ++e)
      v[i*8 + e] = __uint_as_float(((unsigned)(u16)x[e]) << 16);
  }

  float lv[MAXT];
#pragma unroll
  for (int k = 0; k < MAXT; ++k) lv[k] = NEG_INF;
#pragma unroll
  for (int i = 0; i < 32; ++i)
    if (v[i] > lv[MAXT - 1]) insert_val(lv, v[i]);

  float mk = NEG_INF;
  for (int r = 0; r < K; ++r) {
    float bv = lv[0]; int bl = l;
#pragma unroll
    for (int it = 0; it < 6; ++it) {
      float ov = __shfl_xor(bv, 1 << it);
      int   ol = __shfl_xor(bl, 1 << it);
      if (ov > bv || (ov == bv && ol < bl)) { bv = ov; bl = ol; }
    }
    mk = bv;
    if (l == bl) {
#pragma unroll
      for (int k = 0; k < MAXT - 1; ++k) lv[k] = lv[k + 1];
      lv[MAXT - 1] = NEG_INF;
    }
  }
  const float tau = mk - MARGIN;

  u16* out = clist + (size_t)q * CLCAP;
  int cnt = 0;
#pragma unroll
  for (int i = 0; i < 4; ++i)
#pragma unroll
    for (int e = 0; e < 8; ++e) {
      const bool p = (v[i*8 + e] >= tau);
      const unsigned long long b = __ballot(p);
      if (p) {
        const int pos = cnt + (int)__popcll(b & ((1ull << l) - 1ull));
        if (pos < CLCAP) out[pos] = (u16)(i*512 + l*8 + e);
      }
      cnt += (int)__popcll(b);
    }
  if (l == 0) ccount[q] = (cnt > CLCAP) ? CLCAP : cnt;
}

// ---------------- K2c: exact fp32 rescore; one BLOCK (4 waves) per query ----
// waves stride the chunk list; per-lane top-16; per-wave drain to LDS;
// wave 0 merges 4 sorted lists; block-wide gather. Same fmaf chain as before.
__global__ __launch_bounds__(256)
void rescore_kernel(const float* __restrict__ mem, const float* __restrict__ emb,
                    const float* __restrict__ qry, const int* __restrict__ wpp,
                    const float* __restrict__ rm, const float* __restrict__ rq,
                    const u16* __restrict__ clist, const int* __restrict__ ccount,
                    float* __restrict__ out_retr, float* __restrict__ out_vals,
                    int N, int B, int Q, int K) {
  __shared__ float wvS[4 * MAXT];
  __shared__ int   wiS[4 * MAXT];
  __shared__ int   eiS[MAXT];
  const int tid = threadIdx.x;
  const int w = tid >> 6, l = tid & 63;
  const int q = blockIdx.x;
  const int wp = *wpp;

  float4 qv[16];
  {
    const float4* qr4 = (const float4*)(qry + (size_t)q * DIM);
#pragma unroll
    for (int d = 0; d < 16; ++d) qv[d] = qr4[d];
  }
  const float rqv = rq[q];
  const int cnt = ccount[q];
  const u16* cl = clist + (size_t)q * CLCAP;

  float lv[MAXT]; int li[MAXT];
#pragma unroll
  for (int k = 0; k < MAXT; ++k) { lv[k] = NEG_INF; li[k] = 0x7fffffff; }

  for (int i = w; i < cnt; i += 4) {
    const int row = (int)cl[i] * CHUNK + l;
    const float* mr = row_src(row, mem, emb, wp, N, B);
    float acc = 0.f;
#pragma unroll
    for (int d = 0; d < 16; ++d) {
      float4 m4 = *(const float4*)(mr + d*4);
      float4 q4 = qv[d];
      acc = fmaf(q4.x, m4.x, acc); acc = fmaf(q4.y, m4.y, acc);
      acc = fmaf(q4.z, m4.z, acc); acc = fmaf(q4.w, m4.w, acc);
    }
    const float vv = acc * rqv * rm[row];
    if (rank_below(lv[MAXT - 1], li[MAXT - 1], vv, row)) insert_pair(lv, li, vv, row);
  }

  // per-wave drain: wave's top-K (sorted) -> LDS
  for (int r = 0; r < K; ++r) {
    float bv = lv[0]; int bi = li[0];
#pragma unroll
    for (int it = 0; it < 6; ++it) {
      float ov = __shfl_xor(bv, 1 << it);
      int   oi = __shfl_xor(bi, 1 << it);
      if (ov > bv || (ov == bv && oi < bi)) { bv = ov; bi = oi; }
    }
    if (li[0] == bi) {
#pragma unroll
      for (int k = 0; k < MAXT - 1; ++k) { lv[k] = lv[k + 1]; li[k] = li[k + 1]; }
      lv[MAXT - 1] = NEG_INF; li[MAXT - 1] = 0x7fffffff;
    }
    if (l == 0) { wvS[w*MAXT + r] = bv; wiS[w*MAXT + r] = bi; }
  }
  __syncthreads();

  // wave 0: 4-way merge of sorted lists, K rounds
  if (w == 0) {
    int hp = 0;
    float hv = NEG_INF; int hi = 0x7fffffff;
    if (l < 4) { hv = wvS[l*MAXT]; hi = wiS[l*MAXT]; }
    for (int r = 0; r < K; ++r) {
      float bv = hv; int bi = hi; int bs = (l < 4) ? l : 0x7fffffff;
#pragma unroll
      for (int it = 0; it < 2; ++it) {     // masks 1,2 mix within 4-lane quad
        float ov = __shfl_xor(bv, 1 << it);
        int   oi = __shfl_xor(bi, 1 << it);
        int   os = __shfl_xor(bs, 1 << it);
        if (ov > bv || (ov == bv && oi < bi)) { bv = ov; bi = oi; bs = os; }
      }
      if (l == 0) { out_vals[(size_t)q * K + r] = bv; eiS[r] = bi; }
      if (l < 4 && l == bs) {
        ++hp;
        if (hp < K) { hv = wvS[l*MAXT + hp]; hi = wiS[l*MAXT + hp]; }
        else        { hv = NEG_INF;          hi = 0x7fffffff;       }
      }
    }
  }
  __syncthreads();

  for (int e = tid; e < K * DIM; e += 256) {
    const int kk = e >> 6, d = e & 63;
    const float* mr = row_src(eiS[kk], mem, emb, wp, N, B);
    out_retr[((size_t)q * K + kk) * DIM + d] = mr[d];
  }
}

// ---------------- host launch ----------------
extern "C" void kernel_launch(void* const* d_in, const int* in_sizes, int n_in,
                              void* d_out, int out_size, void* d_ws, size_t ws_size,
                              hipStream_t stream) {
  const float* mem = (const float*)d_in[0];
  const float* emb = (const float*)d_in[1];
  const float* qry = (const float*)d_in[2];
  const int*   wpp = (const int*)d_in[3];

  const int N = in_sizes[0] / DIM;     // 131072
  const int B = in_sizes[1] / DIM;     // 4096
  const int Q = in_sizes[2] / DIM;     // 2048
  int K = out_size / (Q * (DIM + 1));  // 10
  if (K < 1) K = 1;
  if (K > MAXT) K = MAXT;
  const int nchTotal = N / CHUNK;      // 2048

  float* rm    = (float*)d_ws;
  float* rq    = rm + N;
  u16*   Cmax  = (u16*)(rq + Q);
  u16*   clist = Cmax + (size_t)Q * nchTotal;
  int*   ccount= (int*)(clist + (size_t)Q * CLCAP);
  u16*   Mn    = (u16*)(ccount + Q);
  u16*   Qn    = Mn + (size_t)N * DIM;

  float* out_retr = (float*)d_out;
  float* out_vals = (float*)d_out + (size_t)Q * K * DIM;

  prep_kernel<<<(N + Q) / 32, 256, 0, stream>>>(mem, emb, qry, wpp, rm, rq, Mn, Qn, N, B, Q);

  dim3 g2(Q / QB, SLICES);
  chunkmax_kernel<<<g2, 256, 0, stream>>>(Mn, Qn, Cmax, N, nchTotal);

  select_kernel<<<Q / 4, 256, 0, stream>>>(Cmax, clist, ccount, nchTotal, K);

  rescore_kernel<<<Q, 256, 0, stream>>>(mem, emb, qry, wpp, rm, rq, clist, ccount,
                                        out_retr, out_vals, N, B, Q, K);
}

// Round 5
// 226.028 us; speedup vs baseline: 7.6209x; 1.3118x over previous
//
#include <hip/hip_runtime.h>
#include <math.h>

#define DIM    64
#define MAXT   16
#define SLICES 64
#define QB     128
#define CH     16            // selection chunk = 16 rows
#define CLCAP  2048
#define NEG_INF (-3.0e38f)
#define MARGIN 0.008f

typedef float f32x4 __attribute__((ext_vector_type(4)));
typedef _Float16 f16x8 __attribute__((ext_vector_type(8)));
typedef unsigned short u16;

__device__ __forceinline__ u16 f2bf(float f) {  // RNE f32->bf16
  unsigned u = __float_as_uint(f);
  u += 0x7fffu + ((u >> 16) & 1u);
  return (u16)(u >> 16);
}
__device__ __forceinline__ u16 f2h(float f) {   // RNE f32->fp16 bits
  union { _Float16 h; u16 u; } c; c.h = (_Float16)f; return c.u;
}

__device__ __forceinline__ const float* row_src(int r, const float* __restrict__ mem,
                                                const float* __restrict__ emb,
                                                int wp, int N, int B) {
  int diff = r - wp; if (diff < 0) diff += N;
  return (diff < B) ? (emb + (size_t)diff * DIM) : (mem + (size_t)r * DIM);
}

__device__ __forceinline__ bool rank_below(float a_v, int a_i, float v, int id) {
  return (a_v < v) || (a_v == v && a_i > id);
}

__device__ __forceinline__ void insert_val(float (&lv)[MAXT], float v) {
#pragma unroll
  for (int k = MAXT - 1; k > 0; --k) {
    if (lv[k - 1] < v)      { lv[k] = lv[k - 1]; }
    else if (lv[k] < v)     { lv[k] = v;         }
  }
  if (lv[0] < v) lv[0] = v;
}

__device__ __forceinline__ void insert_pair(float (&lv)[MAXT], int (&li)[MAXT],
                                            float v, int id) {
#pragma unroll
  for (int k = MAXT - 1; k > 0; --k) {
    if (rank_below(lv[k - 1], li[k - 1], v, id)) { lv[k] = lv[k - 1]; li[k] = li[k - 1]; }
    else if (rank_below(lv[k], li[k], v, id))    { lv[k] = v;         li[k] = id;        }
  }
  if (rank_below(lv[0], li[0], v, id)) { lv[0] = v; li[0] = id; }
}

// ---------------- K1: normalize updated memory + queries -> fp16; store inv-norms
__global__ __launch_bounds__(256)
void prep_kernel(const float* __restrict__ mem, const float* __restrict__ emb,
                 const float* __restrict__ qry, const int* __restrict__ wpp,
                 float* __restrict__ rm, float* __restrict__ rq,
                 u16* __restrict__ Mn, u16* __restrict__ Qn,
                 int N, int B, int Q) {
  const int wp  = *wpp;
  const int row = blockIdx.x * 32 + (threadIdx.x >> 3);
  const int sub = threadIdx.x & 7;
  if (row >= N + Q) return;
  const float* src = (row < N) ? row_src(row, mem, emb, wp, N, B)
                               : (qry + (size_t)(row - N) * DIM);
  const float4* s4 = (const float4*)src + sub * 2;
  float4 a = s4[0], b = s4[1];
  float ss = a.x*a.x + a.y*a.y + a.z*a.z + a.w*a.w
           + b.x*b.x + b.y*b.y + b.z*b.z + b.w*b.w;
  ss += __shfl_xor(ss, 1);
  ss += __shfl_xor(ss, 2);
  ss += __shfl_xor(ss, 4);
  const float inv = 1.0f / fmaxf(sqrtf(ss), 1e-12f);
  uint4 o;
  o.x = (unsigned)f2h(a.x*inv) | ((unsigned)f2h(a.y*inv) << 16);
  o.y = (unsigned)f2h(a.z*inv) | ((unsigned)f2h(a.w*inv) << 16);
  o.z = (unsigned)f2h(b.x*inv) | ((unsigned)f2h(b.y*inv) << 16);
  o.w = (unsigned)f2h(b.z*inv) | ((unsigned)f2h(b.w*inv) << 16);
  u16* dst = (row < N) ? (Mn + (size_t)row * DIM + sub * 8)
                       : (Qn + (size_t)(row - N) * DIM + sub * 8);
  *(uint4*)dst = o;
  if (sub == 0) { if (row < N) rm[row] = inv; else rq[row - N] = inv; }
}

// ---------------- K2a: fp16 MFMA, swapped operands -> per-(q,16-row) max ----
// D = mfma(A=mem rows, B=queries): row(=mem)=(l>>4)*4+reg, col(=query)=l&15.
// chunk16 max = 3 in-lane fmax + ds_swizzle(xor16) + shfl(xor32).
// grid 16x64 (XCD-remapped); 4 waves; wave owns q-subtiles 2w,2w+1.
__global__ __launch_bounds__(256, 4)
void chunkmax_kernel(const u16* __restrict__ Mn, const u16* __restrict__ Qn,
                     u16* __restrict__ Cmax, int N, int nch) {
  __shared__ u16 Mb[2][128 * DIM];              // 2 x 16 KB
  const int tid = threadIdx.x;
  const int w = tid >> 6, l = tid & 63;

  const int id = blockIdx.x + gridDim.x * blockIdx.y;
  const int s  = (id & 7) * 8 + (id >> 7);      // slice 0..63
  const int qb = (id >> 3) & 15;
  const int q0 = qb * QB;
  const int slice_rows = N / SLICES;            // 2048
  const int niter = slice_rows / 128;           // 16
  const int row_base = s * slice_rows;

  // B fragments = queries: col n = l&15, k = (l>>4)*8 + ks*32
  f16x8 qF[2][2];
#pragma unroll
  for (int j = 0; j < 2; ++j)
#pragma unroll
    for (int ks = 0; ks < 2; ++ks)
      qF[j][ks] = *(const f16x8*)(Qn + (size_t)(q0 + (2*w + j)*16 + (l & 15)) * DIM
                                      + ks*32 + (l >> 4)*8);

  // staging: instr t covers rows w*32 + t*8 + (l>>3); global 16B-block (l&7)^(l>>3)
  const int sblk = (l & 7) ^ (l >> 3);
  // A-frag read: row r (bits r&7 == l&7), block (l>>4)^(l&7), ks flips +64B
  const int rbase = (l & 15)*128 + (((l >> 4) ^ (l & 7)) << 4);

  int buf = 0;
  {
    char* lb = (char*)&Mb[0][0] + w*4096;
#pragma unroll
    for (int t = 0; t < 4; ++t) {
      const u16* g = Mn + (size_t)(row_base + w*32 + t*8 + (l >> 3)) * DIM + sblk*8;
      __builtin_amdgcn_global_load_lds((const __attribute__((address_space(1))) unsigned int*)g,
                                       (__attribute__((address_space(3))) unsigned int*)(lb + t*1024), 16, 0, 0);
    }
  }
  __syncthreads();

  for (int c2 = 0; c2 < niter; ++c2) {
    if (c2 + 1 < niter) {
      char* lb = (char*)&Mb[buf ^ 1][0] + w*4096;
      const int rb = row_base + (c2 + 1)*128;
#pragma unroll
      for (int t = 0; t < 4; ++t) {
        const u16* g = Mn + (size_t)(rb + w*32 + t*8 + (l >> 3)) * DIM + sblk*8;
        __builtin_amdgcn_global_load_lds((const __attribute__((address_space(1))) unsigned int*)g,
                                         (__attribute__((address_space(3))) unsigned int*)(lb + t*1024), 16, 0, 0);
      }
    }
    const char* lb = (const char*)&Mb[buf][0];
    float cm[2][8];
#pragma unroll
    for (int t = 0; t < 8; ++t) {               // 8 chunk16 tiles in buffer
      f16x8 aM0 = *(const f16x8*)(lb + t*2048 + rbase);
      f16x8 aM1 = *(const f16x8*)(lb + t*2048 + (rbase ^ 64));
#pragma unroll
      for (int j = 0; j < 2; ++j) {
        f32x4 acc = {0.f, 0.f, 0.f, 0.f};
        acc = __builtin_amdgcn_mfma_f32_16x16x32_f16(aM0, qF[j][0], acc, 0, 0, 0);
        acc = __builtin_amdgcn_mfma_f32_16x16x32_f16(aM1, qF[j][1], acc, 0, 0, 0);
        float t1 = fmaxf(fmaxf(acc[0], acc[1]), fmaxf(acc[2], acc[3]));
        float t2 = fmaxf(t1, __int_as_float(
                     __builtin_amdgcn_ds_swizzle(__float_as_int(t1), 0x401F)));  // xor 16
        float t3 = fmaxf(t2, __shfl_xor(t2, 32));                                // xor 32
        cm[j][t] = t3;
      }
    }
    if (l < 16) {
#pragma unroll
      for (int j = 0; j < 2; ++j) {
        uint4 o;
        o.x = (unsigned)f2bf(cm[j][0]) | ((unsigned)f2bf(cm[j][1]) << 16);
        o.y = (unsigned)f2bf(cm[j][2]) | ((unsigned)f2bf(cm[j][3]) << 16);
        o.z = (unsigned)f2bf(cm[j][4]) | ((unsigned)f2bf(cm[j][5]) << 16);
        o.w = (unsigned)f2bf(cm[j][6]) | ((unsigned)f2bf(cm[j][7]) << 16);
        const int q = q0 + (2*w + j)*16 + l;
        *(uint4*)(Cmax + (size_t)q * nch + s*128 + c2*8) = o;
      }
    }
    __syncthreads();
    buf ^= 1;
  }
}

// ---------------- K2b: tau = (K-th largest chunk-max) - MARGIN; compact ids -
// one wave per query; 8192 bf16 maxes streamed twice (tau pass, compact pass).
__global__ __launch_bounds__(256)
void select_kernel(const u16* __restrict__ Cmax, u16* __restrict__ clist,
                   int* __restrict__ ccount, int nch, int K) {
  const int w = threadIdx.x >> 6, l = threadIdx.x & 63;
  const int q = blockIdx.x * 4 + w;
  const u16* row = Cmax + (size_t)q * nch;
  typedef short s16x8 __attribute__((ext_vector_type(8)));

  float lv[MAXT];
#pragma unroll
  for (int k = 0; k < MAXT; ++k) lv[k] = NEG_INF;

#pragma unroll 4
  for (int i = 0; i < 16; ++i) {
    s16x8 x = *(const s16x8*)(row + i*512 + l*8);
#pragma unroll
    for (int e = 0; e < 8; ++e) {
      float v = __uint_as_float(((unsigned)(u16)x[e]) << 16);
      if (v > lv[MAXT - 1]) insert_val(lv, v);
    }
  }

  float mk = NEG_INF;
  for (int r = 0; r < K; ++r) {
    float bv = lv[0]; int bl = l;
#pragma unroll
    for (int it = 0; it < 6; ++it) {
      float ov = __shfl_xor(bv, 1 << it);
      int   ol = __shfl_xor(bl, 1 << it);
      if (ov > bv || (ov == bv && ol < bl)) { bv = ov; bl = ol; }
    }
    mk = bv;
    if (l == bl) {
#pragma unroll
      for (int k = 0; k < MAXT - 1; ++k) lv[k] = lv[k + 1];
      lv[MAXT - 1] = NEG_INF;
    }
  }
  const float tau = mk - MARGIN;

  u16* out = clist + (size_t)q * CLCAP;
  int cnt = 0;
#pragma unroll 4
  for (int i = 0; i < 16; ++i) {
    s16x8 x = *(const s16x8*)(row + i*512 + l*8);
#pragma unroll
    for (int e = 0; e < 8; ++e) {
      const bool p = (__uint_as_float(((unsigned)(u16)x[e]) << 16) >= tau);
      const unsigned long long b = __ballot(p);
      if (p) {
        const int pos = cnt + (int)__popcll(b & ((1ull << l) - 1ull));
        if (pos < CLCAP) out[pos] = (u16)(i*512 + l*8 + e);
      }
      cnt += (int)__popcll(b);
    }
  }
  if (l == 0) ccount[q] = (cnt > CLCAP) ? CLCAP : cnt;
}

// ---------------- K2c: exact fp32 rescore; one block (4 waves) per query ----
// wave-iter covers 4 chunk16s (lane: chunk l>>4, row l&15). Same fmaf chain.
__global__ __launch_bounds__(256)
void rescore_kernel(const float* __restrict__ mem, const float* __restrict__ emb,
                    const float* __restrict__ qry, const int* __restrict__ wpp,
                    const float* __restrict__ rm, const float* __restrict__ rq,
                    const u16* __restrict__ clist, const int* __restrict__ ccount,
                    float* __restrict__ out_retr, float* __restrict__ out_vals,
                    int N, int B, int Q, int K) {
  __shared__ float wvS[4 * MAXT];
  __shared__ int   wiS[4 * MAXT];
  __shared__ int   eiS[MAXT];
  const int tid = threadIdx.x;
  const int w = tid >> 6, l = tid & 63;
  const int q = blockIdx.x;
  const int wp = *wpp;

  float4 qv[16];
  {
    const float4* qr4 = (const float4*)(qry + (size_t)q * DIM);
#pragma unroll
    for (int d = 0; d < 16; ++d) qv[d] = qr4[d];
  }
  const float rqv = rq[q];
  const int cnt = ccount[q];
  const u16* cl = clist + (size_t)q * CLCAP;

  float lv[MAXT]; int li[MAXT];
#pragma unroll
  for (int k = 0; k < MAXT; ++k) { lv[k] = NEG_INF; li[k] = 0x7fffffff; }

  for (int i = w*4; i < cnt; i += 16) {
    const int ci_ = i + (l >> 4);
    const bool valid = (ci_ < cnt);
    const int ch = valid ? (int)cl[ci_] : 0;
    const int row = ch * CH + (l & 15);
    const float* mr = row_src(row, mem, emb, wp, N, B);
    float acc = 0.f;
#pragma unroll
    for (int d = 0; d < 16; ++d) {
      float4 m4 = *(const float4*)(mr + d*4);
      float4 q4 = qv[d];
      acc = fmaf(q4.x, m4.x, acc); acc = fmaf(q4.y, m4.y, acc);
      acc = fmaf(q4.z, m4.z, acc); acc = fmaf(q4.w, m4.w, acc);
    }
    const float vv = valid ? acc * rqv * rm[row] : NEG_INF;
    const int  rid = valid ? row : 0x7fffffff;
    if (rank_below(lv[MAXT - 1], li[MAXT - 1], vv, rid)) insert_pair(lv, li, vv, rid);
  }

  for (int r = 0; r < K; ++r) {
    float bv = lv[0]; int bi = li[0];
#pragma unroll
    for (int it = 0; it < 6; ++it) {
      float ov = __shfl_xor(bv, 1 << it);
      int   oi = __shfl_xor(bi, 1 << it);
      if (ov > bv || (ov == bv && oi < bi)) { bv = ov; bi = oi; }
    }
    if (li[0] == bi) {
#pragma unroll
      for (int k = 0; k < MAXT - 1; ++k) { lv[k] = lv[k + 1]; li[k] = li[k + 1]; }
      lv[MAXT - 1] = NEG_INF; li[MAXT - 1] = 0x7fffffff;
    }
    if (l == 0) { wvS[w*MAXT + r] = bv; wiS[w*MAXT + r] = bi; }
  }
  __syncthreads();

  if (w == 0) {
    int hp = 0;
    float hv = NEG_INF; int hi = 0x7fffffff;
    if (l < 4) { hv = wvS[l*MAXT]; hi = wiS[l*MAXT]; }
    for (int r = 0; r < K; ++r) {
      float bv = hv; int bi = hi; int bs = (l < 4) ? l : 0x7fffffff;
#pragma unroll
      for (int it = 0; it < 2; ++it) {
        float ov = __shfl_xor(bv, 1 << it);
        int   oi = __shfl_xor(bi, 1 << it);
        int   os = __shfl_xor(bs, 1 << it);
        if (ov > bv || (ov == bv && oi < bi)) { bv = ov; bi = oi; bs = os; }
      }
      if (l == 0) { out_vals[(size_t)q * K + r] = bv; eiS[r] = bi; }
      if (l < 4 && l == bs) {
        ++hp;
        if (hp < K) { hv = wvS[l*MAXT + hp]; hi = wiS[l*MAXT + hp]; }
        else        { hv = NEG_INF;          hi = 0x7fffffff;       }
      }
    }
  }
  __syncthreads();

  for (int e = tid; e < K * DIM; e += 256) {
    const int kk = e >> 6, d = e & 63;
    const float* mr = row_src(eiS[kk], mem, emb, wp, N, B);
    out_retr[((size_t)q * K + kk) * DIM + d] = mr[d];
  }
}

// ---------------- host launch ----------------
extern "C" void kernel_launch(void* const* d_in, const int* in_sizes, int n_in,
                              void* d_out, int out_size, void* d_ws, size_t ws_size,
                              hipStream_t stream) {
  const float* mem = (const float*)d_in[0];
  const float* emb = (const float*)d_in[1];
  const float* qry = (const float*)d_in[2];
  const int*   wpp = (const int*)d_in[3];

  const int N = in_sizes[0] / DIM;     // 131072
  const int B = in_sizes[1] / DIM;     // 4096
  const int Q = in_sizes[2] / DIM;     // 2048
  int K = out_size / (Q * (DIM + 1));  // 10
  if (K < 1) K = 1;
  if (K > MAXT) K = MAXT;
  const int nch = N / CH;              // 8192

  // ws: rm[N] | rq[Q] | Cmax[Q*nch] u16 | clist[Q*CLCAP] u16 | ccount[Q] | Mn | Qn  (~60 MB)
  float* rm    = (float*)d_ws;
  float* rq    = rm + N;
  u16*   Cmax  = (u16*)(rq + Q);
  u16*   clist = Cmax + (size_t)Q * nch;
  int*   ccount= (int*)(clist + (size_t)Q * CLCAP);
  u16*   Mn    = (u16*)(ccount + Q);
  u16*   Qn    = Mn + (size_t)N * DIM;

  float* out_retr = (float*)d_out;
  float* out_vals = (float*)d_out + (size_t)Q * K * DIM;

  prep_kernel<<<(N + Q) / 32, 256, 0, stream>>>(mem, emb, qry, wpp, rm, rq, Mn, Qn, N, B, Q);

  dim3 g2(Q / QB, SLICES);
  chunkmax_kernel<<<g2, 256, 0, stream>>>(Mn, Qn, Cmax, N, nch);

  select_kernel<<<Q / 4, 256, 0, stream>>>(Cmax, clist, ccount, nch, K);

  rescore_kernel<<<Q, 256, 0, stream>>>(mem, emb, qry, wpp, rm, rq, clist, ccount,
                                        out_retr, out_vals, N, B, Q, K);
}